// Round 4
// baseline (175.385 us; speedup 1.0000x reference)
//
#include <hip/hip_runtime.h>

// Reference collapses to: val = sum(W2 @ relu(W1[:,0] + b1) + b2), broadcast
// to [B=8, OC=64, H=224, W=224] fp32 (25,690,112 elements = 98 MiB of writes).
//
// Input order: x[unused], W1[256*65536], b1[256], W2[64*256], b2[64], params[unused]
//
// Single fused kernel: every block redundantly computes val (cheap: W1 col 0 is
// 256 cache lines, W2 is 64 KB -> L2-resident after first blocks), then fills a
// contiguous chunk of the output with nontemporal float4 stores.

#define DIM   65536
#define HID   256
#define OC_N  64
#define OUT_N (8ULL * 64 * 224 * 224)  // 25,690,112 floats, divisible by 4
#define NBLK  2048

typedef float f32x4 __attribute__((ext_vector_type(4)));

__global__ void __launch_bounds__(256, 8)
fused_fill_kernel(const float* __restrict__ W1,
                  const float* __restrict__ b1,
                  const float* __restrict__ W2,
                  const float* __restrict__ b2,
                  f32x4* __restrict__ out) {
    const int t = threadIdx.x;  // 0..255 == HID

    // hidden[t] = relu(W1[t, 0] + b1[t]); W1 row-major [HID, DIM] -> stride DIM
    float hidden = W1[(size_t)t * DIM] + b1[t];
    hidden = hidden > 0.0f ? hidden : 0.0f;

    // colsum[t] = sum_oc W2[oc, t]; consecutive threads -> coalesced each iter
    float colsum = 0.0f;
#pragma unroll
    for (int oc = 0; oc < OC_N; ++oc) {
        colsum += W2[oc * HID + t];
    }

    float partial = hidden * colsum + (t < OC_N ? b2[t] : 0.0f);

    // wave64 down-reduce
#pragma unroll
    for (int off = 32; off > 0; off >>= 1) {
        partial += __shfl_down(partial, off, 64);
    }

    __shared__ float smem[4];
    __shared__ float s_val;
    if ((t & 63) == 0) smem[t >> 6] = partial;
    __syncthreads();
    if (t == 0) s_val = smem[0] + smem[1] + smem[2] + smem[3];
    __syncthreads();

    const float v = s_val;
    f32x4 v4 = {v, v, v, v};

    // Contiguous chunk per block: n4 = 6,422,528 float4s over 2048 blocks
    // = 3136 float4s/block = 12.25 iters of 256 threads. Last partial iter
    // handled by the bounds check.
    const size_t n4 = OUT_N / 4;
    const size_t per_blk = (n4 + NBLK - 1) / NBLK;          // 3136
    const size_t begin = (size_t)blockIdx.x * per_blk;
    const size_t end = begin + per_blk < n4 ? begin + per_blk : n4;
    for (size_t i = begin + t; i < end; i += 256) {
        __builtin_nontemporal_store(v4, &out[i]);
    }
}

extern "C" void kernel_launch(void* const* d_in, const int* in_sizes, int n_in,
                              void* d_out, int out_size, void* d_ws, size_t ws_size,
                              hipStream_t stream) {
    const float* W1 = (const float*)d_in[1];
    const float* b1 = (const float*)d_in[2];
    const float* W2 = (const float*)d_in[3];
    const float* b2 = (const float*)d_in[4];

    // 2048 blocks x 256 threads = 8 blocks/CU, 32 waves/CU: saturates write BW
    fused_fill_kernel<<<NBLK, 256, 0, stream>>>(W1, b1, W2, b2, (f32x4*)d_out);
}

// Round 5
// 162.279 us; speedup vs baseline: 1.0808x; 1.0808x over previous
//
#include <hip/hip_runtime.h>

// Reference collapses to: val = sum(W2 @ relu(W1[:,0] + b1) + b2), broadcast
// to [B=8, OC=64, H=224, W=224] fp32 (25,690,112 elements = 98 MiB of writes).
//
// Input order: x[unused], W1[256*65536], b1[256], W2[64*256], b2[64], params[unused]
//
// Fused kernel: every block redundantly computes val (cheap: W1 col 0 = 256
// cache lines + W2 = 64 KB, L2-resident after first block per XCD), then fills
// a contiguous chunk of the output with PLAIN float4 stores (matching the
// 6.8 TB/s rocclr fill kernels; nontemporal regressed Round 4 by ~20 us).

#define DIM   65536
#define HID   256
#define OC_N  64
#define OUT_N (8ULL * 64 * 224 * 224)  // 25,690,112 floats, divisible by 4
#define NBLK  2048

typedef float f32x4 __attribute__((ext_vector_type(4)));

__global__ void __launch_bounds__(256, 8)
fused_fill_kernel(const float* __restrict__ W1,
                  const float* __restrict__ b1,
                  const float* __restrict__ W2,
                  const float* __restrict__ b2,
                  f32x4* __restrict__ out) {
    const int t = threadIdx.x;  // 0..255 == HID

    // hidden[t] = relu(W1[t, 0] + b1[t]); W1 row-major [HID, DIM] -> stride DIM
    float hidden = W1[(size_t)t * DIM] + b1[t];
    hidden = hidden > 0.0f ? hidden : 0.0f;

    // colsum[t] = sum_oc W2[oc, t]; consecutive threads -> coalesced each iter
    float colsum = 0.0f;
#pragma unroll
    for (int oc = 0; oc < OC_N; ++oc) {
        colsum += W2[oc * HID + t];
    }

    float partial = hidden * colsum + (t < OC_N ? b2[t] : 0.0f);

    // wave64 down-reduce
#pragma unroll
    for (int off = 32; off > 0; off >>= 1) {
        partial += __shfl_down(partial, off, 64);
    }

    __shared__ float smem[4];
    __shared__ float s_val;
    if ((t & 63) == 0) smem[t >> 6] = partial;
    __syncthreads();
    if (t == 0) s_val = smem[0] + smem[1] + smem[2] + smem[3];
    __syncthreads();

    const float v = s_val;
    f32x4 v4 = {v, v, v, v};

    // Contiguous chunk per block: n4 = 6,422,528 float4s over 2048 blocks
    // = 3136 float4s/block = 12.25 iters of 256 threads.
    const size_t n4 = OUT_N / 4;
    const size_t per_blk = (n4 + NBLK - 1) / NBLK;          // 3136
    const size_t begin = (size_t)blockIdx.x * per_blk;
    const size_t end = begin + per_blk < n4 ? begin + per_blk : n4;
    for (size_t i = begin + t; i < end; i += 256) {
        out[i] = v4;  // plain store: let L2 write-back aggregate
    }
}

extern "C" void kernel_launch(void* const* d_in, const int* in_sizes, int n_in,
                              void* d_out, int out_size, void* d_ws, size_t ws_size,
                              hipStream_t stream) {
    const float* W1 = (const float*)d_in[1];
    const float* b1 = (const float*)d_in[2];
    const float* W2 = (const float*)d_in[3];
    const float* b2 = (const float*)d_in[4];

    // 2048 blocks x 256 threads = 8 blocks/CU, 32 waves/CU: saturates write BW
    fused_fill_kernel<<<NBLK, 256, 0, stream>>>(W1, b1, W2, b2, (f32x4*)d_out);
}